// Round 1
// baseline (821.298 us; speedup 1.0000x reference)
//
#include <hip/hip_runtime.h>

// ---------------------------------------------------------------------------
// LabeledConv round 3: FUSED aggregate+GEMM.
//   Round 2 materialized Agg (N x 1024 bf16, 205 MB): aggx wrote it (200 MB
//   WRITE) and lc_gemm read it twice (grid.y=2 => 410 MB). This round each
//   GEMM block gathers its own 32x1024 A-tile directly into LDS (64 KB,
//   XOR-swizzled) and multiplies against Wt (512 KB, L2-resident) read
//   straight from global -- no Agg, no Bs staging, no intra-loop barriers.
// ---------------------------------------------------------------------------

typedef __bf16 v8bf __attribute__((ext_vector_type(8)));
typedef float v4f __attribute__((ext_vector_type(4)));

__device__ __forceinline__ unsigned short f2bf(float f) {
  unsigned u = __float_as_uint(f);
  u += 0x7fffu + ((u >> 16) & 1u);  // RNE
  return (unsigned short)(u >> 16);
}
__device__ __forceinline__ float bf2f(unsigned short s) {
  return __uint_as_float(((unsigned)s) << 16);
}

// ---------------------------------------------------------------------------
__global__ void lc_zero(int* __restrict__ p, int n) {
  int i = blockIdx.x * 256 + threadIdx.x;
  if (i < n) p[i] = 0;
}

__global__ void lc_hist(const int* __restrict__ e0, const int* __restrict__ e1,
                        const int* __restrict__ e2, const int* __restrict__ e3,
                        int* __restrict__ hist, int N, int E) {
  int e = blockIdx.x * 256 + threadIdx.x;
  if (e >= E) return;
  int k = blockIdx.y;
  const int* ed = (k == 0) ? e0 : (k == 1) ? e1 : (k == 2) ? e2 : e3;
  int col = ed[E + e];
  atomicAdd(&hist[k * N + col], 1);
}

__global__ void lc_dis(const int* __restrict__ hist, float* __restrict__ dis, int M) {
  int i = blockIdx.x * 256 + threadIdx.x;
  if (i < M) dis[i] = rsqrtf((float)(hist[i] + 1));  // +1 self loop
}

__global__ void lc_scan1(const int* __restrict__ in, int* __restrict__ outp,
                         int* __restrict__ bsum, int M) {
  __shared__ int tmp[256];
  int t = threadIdx.x, i = blockIdx.x * 256 + t;
  int v = (i < M) ? in[i] : 0;
  tmp[t] = v;
  __syncthreads();
  for (int off = 1; off < 256; off <<= 1) {
    int add = (t >= off) ? tmp[t - off] : 0;
    __syncthreads();
    tmp[t] += add;
    __syncthreads();
  }
  if (i < M) outp[i] = tmp[t] - v;
  if (t == 255) bsum[blockIdx.x] = tmp[255];
}

__global__ void lc_scan2(int* __restrict__ bsum, int nb) {
  __shared__ int tmp[256];
  __shared__ int carry_s;
  int t = threadIdx.x;
  if (t == 0) carry_s = 0;
  __syncthreads();
  for (int base = 0; base < nb; base += 256) {
    int i = base + t;
    int v = (i < nb) ? bsum[i] : 0;
    tmp[t] = v;
    __syncthreads();
    for (int off = 1; off < 256; off <<= 1) {
      int add = (t >= off) ? tmp[t - off] : 0;
      __syncthreads();
      tmp[t] += add;
      __syncthreads();
    }
    int carry = carry_s;
    int total = tmp[255];
    if (i < nb) bsum[i] = carry + tmp[t] - v;
    __syncthreads();
    if (t == 0) carry_s = carry + total;
    __syncthreads();
  }
}

__global__ void lc_scan3(int* __restrict__ rp, int* __restrict__ cursor,
                         const int* __restrict__ bsum, int M) {
  int i = blockIdx.x * 256 + threadIdx.x;
  if (i < M) {
    int v = rp[i] + bsum[blockIdx.x];
    rp[i] = v;
    cursor[i] = v;
  }
}

__global__ void lc_fill(const int* __restrict__ e0, const int* __restrict__ e1,
                        const int* __restrict__ e2, const int* __restrict__ e3,
                        int* __restrict__ cursor, const float* __restrict__ dis,
                        int2* __restrict__ payload, int N, int E) {
  int e = blockIdx.x * 256 + threadIdx.x;
  if (e >= E) return;
  int k = blockIdx.y;
  const int* ed = (k == 0) ? e0 : (k == 1) ? e1 : (k == 2) ? e2 : e3;
  int src = ed[e], col = ed[E + e];
  int pos = atomicAdd(&cursor[k * N + col], 1);
  float nrm = dis[k * N + src] * dis[k * N + col];
  payload[pos] = make_int2(src, __float_as_int(nrm));
}

__global__ void lc_bias(const float* __restrict__ b1, const float* __restrict__ b2,
                        const float* __restrict__ b3, const float* __restrict__ b4,
                        const float* __restrict__ p2, const float* __restrict__ p3,
                        const float* __restrict__ p4, const float* __restrict__ p5,
                        float* __restrict__ biasc) {
  int c = threadIdx.x;
  biasc[c] = b1[c] * p2[c] + b2[c] * p3[c] + b3[c] * p4[c] + b4[c] * p5[c];
}

// Wt[co][k*256+kk] = W_k[kk][co] * p_{k+2}[co]  (B operand, rows=out chan, K=1024)
__global__ void lc_prep(const float* __restrict__ W1, const float* __restrict__ W2,
                        const float* __restrict__ W3, const float* __restrict__ W4,
                        const float* __restrict__ p2, const float* __restrict__ p3,
                        const float* __restrict__ p4, const float* __restrict__ p5,
                        unsigned short* __restrict__ Wt) {
  int b = blockIdx.x;
  int k = b >> 8, co = b & 255;
  int kk = threadIdx.x;
  const float* W = (k == 0) ? W1 : (k == 1) ? W2 : (k == 2) ? W3 : W4;
  const float* p = (k == 0) ? p2 : (k == 1) ? p3 : (k == 2) ? p4 : p5;
  Wt[(size_t)co * 1024 + k * 256 + kk] = f2bf(W[kk * 256 + co] * p[co]);
}

// x -> bf16; also m0[n]=t0[n]*x[n,0], m1[n]=t1[n]*x[n,0]
__global__ void lc_cvt(const float4* __restrict__ x4, ushort4* __restrict__ xb4,
                       const float* __restrict__ t0, const float* __restrict__ t1,
                       float* __restrict__ m0, float* __restrict__ m1, int n4) {
  int i = blockIdx.x * 256 + threadIdx.x;
  if (i >= n4) return;
  float4 v = x4[i];
  ushort4 r;
  r.x = f2bf(v.x); r.y = f2bf(v.y); r.z = f2bf(v.z); r.w = f2bf(v.w);
  xb4[i] = r;
  if ((i & 63) == 0) {
    int n = i >> 6;
    float xc = v.x;
    m0[n] = t0[n] * xc;
    m1[n] = t1[n] * xc;
  }
}

// ---------------------------------------------------------------------------
// Fused gather-aggregate + GEMM + epilogue.
//   Block: 512 threads (8 waves), tile = 32 nodes x 256 out cols, K = 1024.
//   Phase 1: wave w aggregates (node, edge-set) pairs [w*16, w*16+16) into
//            As[32][1024] bf16 (XOR-swizzled, conflict-free frag reads).
//            Two edge lists interleaved per iteration => 8 gathers in flight.
//   Phase 2: K-loop, A frags from LDS (static -> NO barriers), B frags from
//            global Wt (L2-resident). 4 MFMA / k-step / wave.
//   LDS 64 KB -> 2 blocks/CU, 16 waves/CU.
// ---------------------------------------------------------------------------
#define GAT1(POS, A0, A1, A2, A3)                                       \
  do {                                                                  \
    int2 ee = payload[POS];                                             \
    ushort4 gg = *(const ushort4*)&xb[(size_t)ee.x * 256 + c];          \
    float nn = __int_as_float(ee.y);                                    \
    A0 += bf2f(gg.x) * nn;                                              \
    A1 += bf2f(gg.y) * nn;                                              \
    A2 += bf2f(gg.z) * nn;                                              \
    A3 += bf2f(gg.w) * nn;                                              \
  } while (0)

__global__ __launch_bounds__(512, 4) void lc_fused(
    const unsigned short* __restrict__ xb, const unsigned short* __restrict__ Wt,
    const int* __restrict__ rp, const int* __restrict__ hist,
    const float* __restrict__ dis, const int2* __restrict__ payload,
    float* __restrict__ out, int N,
    const float* __restrict__ m0, const float* __restrict__ m1,
    const float* __restrict__ p0, const float* __restrict__ p1,
    const float* __restrict__ biasc) {
  __shared__ alignas(16) unsigned short As[32 * 1024];  // 64 KB
  const int t = threadIdx.x;
  const int w = t >> 6, lane = t & 63;
  const int quad = lane >> 4, l16 = lane & 15;
  const int n0 = blockIdx.x * 32;
  const int c = lane * 4;  // 4 channels per lane

  // ---- phase 1: gather-aggregate into As ----
  for (int pb = 0; pb < 16; pb += 2) {
    int pr = w * 16 + pb;  // pair id; pr and pr+1 share the node, k = {k0, k0+1}
    int ln = pr >> 2;      // local node row 0..31
    int k0 = pr & 3;       // even => 0 or 2
    int n = n0 + ln;
    if (n >= N) n = N - 1;  // tail clamp; stores guarded in epilogue
    int idx0 = k0 * N + n;
    int idx1 = idx0 + N;
    float d0 = dis[idx0], d1 = dis[idx1];
    float s0v = d0 * d0, s1v = d1 * d1;  // self-loop norm = 1/deg
    ushort4 hv = *(const ushort4*)&xb[(size_t)n * 256 + c];
    float x0 = bf2f(hv.x), x1 = bf2f(hv.y), x2 = bf2f(hv.z), x3 = bf2f(hv.w);
    float a0 = x0 * s0v, a1 = x1 * s0v, a2 = x2 * s0v, a3 = x3 * s0v;
    float b0 = x0 * s1v, b1 = x1 * s1v, b2 = x2 * s1v, b3 = x3 * s1v;
    int st0 = rp[idx0], cnt0 = hist[idx0];
    int st1 = rp[idx1], cnt1 = hist[idx1];
    int i0 = 0, i1 = 0;
    // dual-list 4-unrolled: 8 independent gathers in flight
    while (i0 + 4 <= cnt0 && i1 + 4 <= cnt1) {
      GAT1(st0 + i0 + 0, a0, a1, a2, a3);
      GAT1(st0 + i0 + 1, a0, a1, a2, a3);
      GAT1(st0 + i0 + 2, a0, a1, a2, a3);
      GAT1(st0 + i0 + 3, a0, a1, a2, a3);
      GAT1(st1 + i1 + 0, b0, b1, b2, b3);
      GAT1(st1 + i1 + 1, b0, b1, b2, b3);
      GAT1(st1 + i1 + 2, b0, b1, b2, b3);
      GAT1(st1 + i1 + 3, b0, b1, b2, b3);
      i0 += 4;
      i1 += 4;
    }
    for (; i0 + 4 <= cnt0; i0 += 4) {
      GAT1(st0 + i0 + 0, a0, a1, a2, a3);
      GAT1(st0 + i0 + 1, a0, a1, a2, a3);
      GAT1(st0 + i0 + 2, a0, a1, a2, a3);
      GAT1(st0 + i0 + 3, a0, a1, a2, a3);
    }
    for (; i0 < cnt0; ++i0) GAT1(st0 + i0, a0, a1, a2, a3);
    for (; i1 + 4 <= cnt1; i1 += 4) {
      GAT1(st1 + i1 + 0, b0, b1, b2, b3);
      GAT1(st1 + i1 + 1, b0, b1, b2, b3);
      GAT1(st1 + i1 + 2, b0, b1, b2, b3);
      GAT1(st1 + i1 + 3, b0, b1, b2, b3);
    }
    for (; i1 < cnt1; ++i1) GAT1(st1 + i1, b0, b1, b2, b3);

    // store both k-blocks of row ln (XOR swizzle on elem bits 3..5)
    unsigned swz = (unsigned)((ln & 7) << 3);
    ushort4 r0, r1;
    r0.x = f2bf(a0); r0.y = f2bf(a1); r0.z = f2bf(a2); r0.w = f2bf(a3);
    r1.x = f2bf(b0); r1.y = f2bf(b1); r1.z = f2bf(b2); r1.w = f2bf(b3);
    *(ushort4*)&As[(unsigned)ln * 1024 + (((unsigned)(k0 * 256 + c)) ^ swz)] = r0;
    *(ushort4*)&As[(unsigned)ln * 1024 + (((unsigned)((k0 + 1) * 256 + c)) ^ swz)] = r1;
  }
  __syncthreads();

  // ---- phase 2: GEMM. wave w owns cols [w*32, w*32+32), all 32 rows ----
  v4f acc[2][2];
#pragma unroll
  for (int mt = 0; mt < 2; mt++)
#pragma unroll
    for (int nt = 0; nt < 2; nt++) {
      v4f z = {0.f, 0.f, 0.f, 0.f};
      acc[mt][nt] = z;
    }

  const unsigned short* Bp = Wt + (size_t)(w * 32 + l16) * 1024 + quad * 8;
#pragma unroll 4
  for (int kk = 0; kk < 1024; kk += 32) {
    // A frag rows: mt*16 + l16 ; (16+l16)&7 == l16&7 so one swizzle for both
    int eq = (kk + quad * 8) ^ ((l16 & 7) << 3);
    v8bf af0 = *(const v8bf*)&As[(unsigned)l16 * 1024 + eq];
    v8bf af1 = *(const v8bf*)&As[(unsigned)(l16 + 16) * 1024 + eq];
    v8bf bq0 = *(const v8bf*)&Bp[kk];           // out-col w*32 + l16
    v8bf bq1 = *(const v8bf*)&Bp[16384 + kk];   // out-col w*32 + 16 + l16
    acc[0][0] = __builtin_amdgcn_mfma_f32_16x16x32_bf16(af0, bq0, acc[0][0], 0, 0, 0);
    acc[0][1] = __builtin_amdgcn_mfma_f32_16x16x32_bf16(af0, bq1, acc[0][1], 0, 0, 0);
    acc[1][0] = __builtin_amdgcn_mfma_f32_16x16x32_bf16(af1, bq0, acc[1][0], 0, 0, 0);
    acc[1][1] = __builtin_amdgcn_mfma_f32_16x16x32_bf16(af1, bq1, acc[1][1], 0, 0, 0);
  }

  // ---- epilogue: C/D layout col=lane&15, row=quad*4+reg ----
  float pc0[2], pc1[2], bcv[2];
#pragma unroll
  for (int nt = 0; nt < 2; nt++) {
    int gcol = w * 32 + nt * 16 + l16;
    pc0[nt] = p0[gcol];
    pc1[nt] = p1[gcol];
    bcv[nt] = biasc[gcol];
  }
#pragma unroll
  for (int mt = 0; mt < 2; mt++)
#pragma unroll
    for (int r = 0; r < 4; r++) {
      int grow = n0 + mt * 16 + quad * 4 + r;
      if (grow >= N) continue;
      float m0v = m0[grow], m1v = m1[grow];
#pragma unroll
      for (int nt = 0; nt < 2; nt++) {
        int gcol = w * 32 + nt * 16 + l16;
        out[(size_t)grow * 256 + gcol] =
            acc[mt][nt][r] + m0v * pc0[nt] + m1v * pc1[nt] + bcv[nt];
      }
    }
}

// ---------------------------------------------------------------------------
extern "C" void kernel_launch(void* const* d_in, const int* in_sizes, int n_in,
                              void* d_out, int out_size, void* d_ws, size_t ws_size,
                              hipStream_t stream) {
  const float* x = (const float*)d_in[0];
  const int* e00 = (const int*)d_in[1];
  const int* e01 = (const int*)d_in[2];
  const int* e10 = (const int*)d_in[3];
  const int* e11 = (const int*)d_in[4];
  const float* t0 = (const float*)d_in[5];
  const float* t1 = (const float*)d_in[6];
  const float* W1 = (const float*)d_in[7];
  const float* b1 = (const float*)d_in[8];
  const float* W2 = (const float*)d_in[9];
  const float* b2 = (const float*)d_in[10];
  const float* W3 = (const float*)d_in[11];
  const float* b3 = (const float*)d_in[12];
  const float* W4 = (const float*)d_in[13];
  const float* b4 = (const float*)d_in[14];
  const float* p0 = (const float*)d_in[15];
  const float* p1 = (const float*)d_in[16];
  const float* p2 = (const float*)d_in[17];
  const float* p3 = (const float*)d_in[18];
  const float* p4 = (const float*)d_in[19];
  const float* p5 = (const float*)d_in[20];
  float* out = (float*)d_out;

  int N = in_sizes[0] / 256;
  int E = in_sizes[1] / 2;
  int M4 = 4 * N;
  int nb = (M4 + 255) / 256;

  char* wp = (char*)d_ws;
  auto carve = [&](size_t bytes) {
    void* r = (void*)wp;
    wp += (bytes + 255) & ~(size_t)255;
    return r;
  };
  unsigned short* xb = (unsigned short*)carve((size_t)N * 256 * 2);
  unsigned short* Wt = (unsigned short*)carve((size_t)256 * 1024 * 2);
  int* hist = (int*)carve((size_t)M4 * 4);
  float* dis = (float*)carve((size_t)M4 * 4);
  int* rp = (int*)carve((size_t)M4 * 4);
  int* cursor = (int*)carve((size_t)M4 * 4);
  int* bsum = (int*)carve((size_t)nb * 4);
  float* biasc = (float*)carve(256 * 4);
  float* m0 = (float*)carve((size_t)N * 4);
  float* m1 = (float*)carve((size_t)N * 4);
  int2* payload = (int2*)carve((size_t)4 * E * 8);

  int gE = (E + 255) / 256;
  int gM = (M4 + 255) / 256;

  lc_zero<<<gM, 256, 0, stream>>>(hist, M4);
  lc_hist<<<dim3(gE, 4), 256, 0, stream>>>(e00, e01, e10, e11, hist, N, E);
  lc_dis<<<gM, 256, 0, stream>>>(hist, dis, M4);
  lc_scan1<<<nb, 256, 0, stream>>>(hist, rp, bsum, M4);
  lc_scan2<<<1, 256, 0, stream>>>(bsum, nb);
  lc_scan3<<<nb, 256, 0, stream>>>(rp, cursor, bsum, M4);
  lc_fill<<<dim3(gE, 4), 256, 0, stream>>>(e00, e01, e10, e11, cursor, dis, payload, N, E);
  lc_bias<<<1, 256, 0, stream>>>(b1, b2, b3, b4, p2, p3, p4, p5, biasc);
  lc_prep<<<1024, 256, 0, stream>>>(W1, W2, W3, W4, p2, p3, p4, p5, Wt);
  lc_cvt<<<(N * 64 + 255) / 256, 256, 0, stream>>>((const float4*)x, (ushort4*)xb,
                                                   t0, t1, m0, m1, N * 64);

  lc_fused<<<dim3((N + 31) / 32), 512, 0, stream>>>(xb, Wt, rp, hist, dis, payload,
                                                    out, N, m0, m1, p0, p1, biasc);
}